// Round 19
// baseline (276.694 us; speedup 1.0000x reference)
//
#include <hip/hip_runtime.h>
#include <hip/hip_bf16.h>

// MultiHeadAttn: B=4, S=2048, D=1024, H=16, HD=64, scale = sqrt(64) = 8
// Pipeline: fused prologue (x cvt + W transposes) | GEMM1 qkv (3-buf counted-vmcnt) |
//           flash attn v13 (max-free exp2 softmax, paired exp2/cvt_pk for low reg peak) |
//           GEMM2 +bias
// v13 = R16's max-free softmax (numerics verified) with the transient register peak
// fixed at the SOURCE: exp2 and v_cvt_pk_bf16_f32 interleaved in pairs so only 2
// p-values are live (R16's 132-VGPR cliff came from 16 live p's). No launch_bounds
// min-waves coercion (R10/R17: cuts unified VGPR+AGPR budget -> spill).

#define S_ 2048
#define D_ 1024

typedef __attribute__((ext_vector_type(4))) float f32x4;
typedef __attribute__((ext_vector_type(16))) float f32x16;
typedef __attribute__((ext_vector_type(8))) short bf16x8;

__device__ __forceinline__ unsigned short f2b(float f) {
  union { float f; unsigned u; } x; x.f = f;
  unsigned r = x.u + 0x7fffu + ((x.u >> 16) & 1u);
  return (unsigned short)(r >> 16);
}
__device__ __forceinline__ float b2f(unsigned short u) {
  union { unsigned u; float f; } x; x.u = ((unsigned)u) << 16; return x.f;
}

__device__ __forceinline__ void gload_lds16(const void* g, void* l) {
  __builtin_amdgcn_global_load_lds(
      (const __attribute__((address_space(1))) unsigned int*)g,
      (__attribute__((address_space(3))) unsigned int*)l, 16, 0, 0);
}

// ---------------- fused prologue: x f32->bf16 + both W transposes ----------------
// grid 8192 x 256: blocks [0,4096) cvt x; [4096,7168) transpose Wqkv; [7168,8192) Wfc.
__global__ __launch_bounds__(256) void prologue(const float* __restrict__ x,
                                                unsigned short* __restrict__ xb,
                                                const float* __restrict__ Wqkv,
                                                unsigned short* __restrict__ wqkvT,
                                                const float* __restrict__ Wfc,
                                                unsigned short* __restrict__ wfcT) {
  __shared__ unsigned short tile[32][33];
  int bid = blockIdx.x;
  if (bid < 4096) {
    int i = (bid * 256 + threadIdx.x) * 8;
    float4 a = *(const float4*)&x[i];
    float4 b = *(const float4*)&x[i + 4];
    unsigned short r[8];
    r[0] = f2b(a.x); r[1] = f2b(a.y); r[2] = f2b(a.z); r[3] = f2b(a.w);
    r[4] = f2b(b.x); r[5] = f2b(b.y); r[6] = f2b(b.z); r[7] = f2b(b.w);
    *(uint4*)&xb[i] = *(uint4*)r;
    return;
  }
  const float* W; unsigned short* Wt; int N, n0, k0;
  if (bid < 7168) {
    int t = bid - 4096;
    W = Wqkv; Wt = wqkvT; N = 3072;
    n0 = (t % 96) * 32; k0 = (t / 96) * 32;
  } else {
    int t = bid - 7168;
    W = Wfc; Wt = wfcT; N = 1024;
    n0 = (t % 32) * 32; k0 = (t / 32) * 32;
  }
  int tx = threadIdx.x & 31, ty = threadIdx.x >> 5;  // 32 x 8
  #pragma unroll
  for (int i = 0; i < 32; i += 8)
    tile[ty + i][tx] = f2b(W[(size_t)(k0 + ty + i) * N + n0 + tx]);
  __syncthreads();
  #pragma unroll
  for (int i = 0; i < 32; i += 8)
    Wt[(size_t)(n0 + ty + i) * 1024 + k0 + tx] = tile[tx][ty + i];
}

// ---------------- GEMM: C[M][N] = A[M][K] * Bt[N][K]^T (R13/R15/R18 exact) ----------------
// 3-buffer counted-vmcnt pipeline: STAGE(kt+2); vmcnt(8); barrier; ds_read+MFMA;
// lgkmcnt(0); barrier. vmcnt never drains to 0 mid-loop. K must be 1024.
__global__ __launch_bounds__(256) void gemm_bt(const unsigned short* __restrict__ A,
                                               const unsigned short* __restrict__ Bt,
                                               const float* __restrict__ bias,
                                               float* __restrict__ Cf,
                                               unsigned short* __restrict__ Cb,
                                               int M, int N, int K) {
  __shared__ unsigned short As[3][128 * 32];
  __shared__ unsigned short Bs[3][128 * 32];
  int tid = threadIdx.x, wave = tid >> 6, lane = tid & 63;
  int bm = blockIdx.x, bn = blockIdx.y;
  int wr = (wave >> 1) * 64, wc = (wave & 1) * 64;
  f32x4 acc[4][4] = {};

  const unsigned short* aBase = A + (size_t)(bm * 128 + wave * 32 + (lane >> 2)) * K + (lane & 3) * 8;
  const unsigned short* bBase = Bt + (size_t)(bn * 128 + wave * 32 + (lane >> 2)) * K + (lane & 3) * 8;
  const size_t row16 = (size_t)16 * K;
  int ldst0 = wave * 1024 + lane * 8;
  int ldst1 = ldst0 + 512;

  #define STAGE_G(kt, sb)                                                      \
    do {                                                                       \
      const unsigned short* ap = aBase + (kt) * 32;                            \
      const unsigned short* bp = bBase + (kt) * 32;                            \
      gload_lds16(ap, &As[sb][ldst0]);                                         \
      gload_lds16(ap + row16, &As[sb][ldst1]);                                 \
      gload_lds16(bp, &Bs[sb][ldst0]);                                         \
      gload_lds16(bp + row16, &Bs[sb][ldst1]);                                 \
    } while (0)

  #define READ_MFMA_G(sb)                                                      \
    do {                                                                       \
      bf16x8 af[4], bf[4];                                                     \
      _Pragma("unroll")                                                        \
      for (int i = 0; i < 4; i++)                                              \
        af[i] = *(const bf16x8*)&As[sb][(wr + i * 16 + (lane & 15)) * 32 + (lane >> 4) * 8]; \
      _Pragma("unroll")                                                        \
      for (int i = 0; i < 4; i++)                                              \
        bf[i] = *(const bf16x8*)&Bs[sb][(wc + i * 16 + (lane & 15)) * 32 + (lane >> 4) * 8]; \
      _Pragma("unroll")                                                        \
      for (int i = 0; i < 4; i++)                                              \
        _Pragma("unroll")                                                      \
        for (int j = 0; j < 4; j++)                                            \
          acc[i][j] = __builtin_amdgcn_mfma_f32_16x16x32_bf16(af[i], bf[j], acc[i][j], 0, 0, 0); \
    } while (0)

  #define TRAIL_SYNC()                                                         \
    do {                                                                       \
      asm volatile("s_waitcnt lgkmcnt(0)" ::: "memory");                       \
      asm volatile("s_barrier" ::: "memory");                                  \
    } while (0)

  STAGE_G(0, 0);
  STAGE_G(1, 1);
  asm volatile("s_waitcnt vmcnt(4)" ::: "memory");
  asm volatile("s_barrier" ::: "memory");

  for (int t3 = 0; t3 < 10; ++t3) {
    int kt = t3 * 3;
    STAGE_G(kt + 2, 2);
    asm volatile("s_waitcnt vmcnt(8)" ::: "memory");
    asm volatile("s_barrier" ::: "memory");
    READ_MFMA_G(0);
    TRAIL_SYNC();
    STAGE_G(kt + 3, 0);
    asm volatile("s_waitcnt vmcnt(8)" ::: "memory");
    asm volatile("s_barrier" ::: "memory");
    READ_MFMA_G(1);
    TRAIL_SYNC();
    STAGE_G(kt + 4, 1);
    asm volatile("s_waitcnt vmcnt(8)" ::: "memory");
    asm volatile("s_barrier" ::: "memory");
    READ_MFMA_G(2);
    TRAIL_SYNC();
  }
  asm volatile("s_waitcnt vmcnt(4)" ::: "memory");
  asm volatile("s_barrier" ::: "memory");
  READ_MFMA_G(0);
  TRAIL_SYNC();
  asm volatile("s_waitcnt vmcnt(0)" ::: "memory");
  asm volatile("s_barrier" ::: "memory");
  READ_MFMA_G(1);
  #undef STAGE_G
  #undef READ_MFMA_G
  #undef TRAIL_SYNC

  int row0 = bm * 128 + wr + (lane >> 4) * 4;
  int col0 = bn * 128 + wc + (lane & 15);
  if (Cb) {
    #pragma unroll
    for (int i = 0; i < 4; i++)
      #pragma unroll
      for (int j = 0; j < 4; j++)
        #pragma unroll
        for (int q = 0; q < 4; q++)
          Cb[(size_t)(row0 + i * 16 + q) * N + col0 + j * 16] = f2b(acc[i][j][q]);
  } else {
    #pragma unroll
    for (int i = 0; i < 4; i++)
      #pragma unroll
      for (int j = 0; j < 4; j++) {
        float bv = bias[col0 + j * 16];
        #pragma unroll
        for (int q = 0; q < 4; q++)
          Cf[(size_t)(row0 + i * 16 + q) * N + col0 + j * 16] = acc[i][j][q] + bv;
      }
  }
}

// ---------------- flash attention v13: max-free exp2 softmax, low register peak ----------------
// grid (64 heads, 8 q-blocks of 256): XCD = bh%8 -> per-XCD K/V L2-resident (T1).
// block 256 = 4 waves; each wave owns q-rows [q0, q0+32) and [q0+128, q0+160).
// Q pre-scaled by log2(e)/8 -> p = exp2f(s) directly (max-free: scores bounded,
// softmax shift-invariant; verified numerically in R16). exp2 and cvt_pk interleaved
// in pairs -> only 2 p-values live at the register-pressure peak (fixes R16's 132 VGPR).
__global__ __launch_bounds__(256) void flash_attn(const unsigned short* __restrict__ qkv,
                                                  unsigned short* __restrict__ ao) {
  __shared__ unsigned short Ks[2][4096];   // [64 kv][64 d], 16B-slot ^ (row&7) swizzle
  __shared__ unsigned short Vs[2][4096];   // [64 d][64 kv], same swizzle
  const float QSCALE = 0.18033688011112042f;  // log2(e) / 8
  int tid = threadIdx.x, wave = tid >> 6, lane = tid & 63;
  int l31 = lane & 31, hi = lane >> 5;
  int bh = blockIdx.x, b = bh >> 4, h = bh & 15;
  const unsigned short* base = qkv + (size_t)b * S_ * 3072 + h * 64;
  const unsigned short* kb = base + 1024;
  const unsigned short* vb = base + 2048;
  int q0 = blockIdx.y * 256 + wave * 32;   // tile A; tile B = q0 + 128

  bf16x8 qfA[4], qfB[4];
  {
    const unsigned short* qpA = base + (size_t)(q0 + l31) * 3072 + hi * 8;
    const unsigned short* qpB = qpA + (size_t)128 * 3072;
    #pragma unroll
    for (int ks = 0; ks < 4; ks++) {
      bf16x8 va = *(const bf16x8*)(qpA + ks * 16);
      bf16x8 vc = *(const bf16x8*)(qpB + ks * 16);
      #pragma unroll
      for (int e = 0; e < 8; e++) {
        va[e] = (short)f2b(QSCALE * b2f((unsigned short)va[e]));
        vc[e] = (short)f2b(QSCALE * b2f((unsigned short)vc[e]));
      }
      qfA[ks] = va; qfB[ks] = vc;
    }
  }

  f32x16 oA0 = {}, oA1 = {}, oB0 = {}, oB1 = {};
  float liA = 0.f, liB = 0.f;   // per-lane partials; partner merged in epilogue

  int r_l = lane >> 3;
  int gsrc = (lane & 7) ^ r_l;
  size_t koffA = (size_t)((wave * 2 + 0) * 8 + r_l) * 3072 + gsrc * 8;
  size_t koffB = (size_t)((wave * 2 + 1) * 8 + r_l) * 3072 + gsrc * 8;
  int kvp = (tid & 31) * 2, dgr = (tid >> 5) * 8;
  int vslot = kvp >> 3;
  int vlo = kvp & 7;
  bf16x8 vr0, vr1;

  {
    gload_lds16(kb + koffA, &Ks[0][(wave * 2 + 0) * 512]);
    gload_lds16(kb + koffB, &Ks[0][(wave * 2 + 1) * 512]);
    const unsigned short* vsrc = vb + (size_t)kvp * 3072 + dgr;
    vr0 = *(const bf16x8*)vsrc;
    vr1 = *(const bf16x8*)(vsrc + 3072);
    union { bf16x8 v; unsigned u[4]; } a0, a1;
    a0.v = vr0; a1.v = vr1;
    #pragma unroll
    for (int i = 0; i < 4; i++) {
      int d0 = dgr + 2 * i, d1 = d0 + 1;
      unsigned we = (a0.u[i] & 0xffffu) | (a1.u[i] << 16);
      unsigned wo = (a0.u[i] >> 16) | (a1.u[i] & 0xffff0000u);
      *(unsigned*)&Vs[0][d0 * 64 + ((vslot ^ (d0 & 7)) << 3) + vlo] = we;
      *(unsigned*)&Vs[0][d1 * 64 + ((vslot ^ (d1 & 7)) << 3) + vlo] = wo;
    }
    __syncthreads();
  }

  for (int t = 0; t < 32; ++t) {
    int cur = t & 1;
    int tn = (t + 1) & 31;
    {
      const unsigned short* ksrc = kb + (size_t)tn * 64 * 3072;
      gload_lds16(ksrc + koffA, &Ks[cur ^ 1][(wave * 2 + 0) * 512]);
      gload_lds16(ksrc + koffB, &Ks[cur ^ 1][(wave * 2 + 1) * 512]);
      const unsigned short* vsrc = vb + (size_t)(tn * 64 + kvp) * 3072 + dgr;
      vr0 = *(const bf16x8*)vsrc;
      vr1 = *(const bf16x8*)(vsrc + 3072);
    }

    const unsigned short* Kc = Ks[cur];
    const unsigned short* Vc = Vs[cur];

    #pragma unroll
    for (int sub = 0; sub < 2; ++sub) {
      f32x16 sA = {}, sB = {};
      __builtin_amdgcn_s_setprio(1);
      #pragma unroll
      for (int ks = 0; ks < 4; ks++) {
        int row = sub * 32 + l31;
        bf16x8 kf = *(const bf16x8*)&Kc[row * 64 + ((((ks << 1) + hi) ^ (row & 7)) << 3)];
        sA = __builtin_amdgcn_mfma_f32_32x32x16_bf16(kf, qfA[ks], sA, 0, 0, 0);
        sB = __builtin_amdgcn_mfma_f32_32x32x16_bf16(kf, qfB[ks], sB, 0, 0, 0);
      }
      __builtin_amdgcn_s_setprio(0);

      // max-free softmax, paired exp2 -> cvt_pk (2 live p's; low register peak)
      union { unsigned u[4]; bf16x8 v; } PA0, PA1;
      {
        unsigned c[8];
        float rs0 = 0.f, rs1 = 0.f;
        #pragma unroll
        for (int r = 0; r < 8; r++) {
          float pe = exp2f(sA[2 * r]);
          float po = exp2f(sA[2 * r + 1]);
          if (r & 1) rs1 += pe + po; else rs0 += pe + po;
          asm("v_cvt_pk_bf16_f32 %0, %1, %2" : "=v"(c[r]) : "v"(pe), "v"(po));
        }
        liA += rs0 + rs1;
        asm volatile("v_permlane32_swap_b32 %0, %1" : "+v"(c[0]), "+v"(c[2]));
        asm volatile("v_permlane32_swap_b32 %0, %1" : "+v"(c[1]), "+v"(c[3]));
        asm volatile("v_permlane32_swap_b32 %0, %1" : "+v"(c[4]), "+v"(c[6]));
        asm volatile("v_permlane32_swap_b32 %0, %1" : "+v"(c[5]), "+v"(c[7]));
        PA0.u[0] = c[0]; PA0.u[1] = c[1]; PA0.u[2] = c[2]; PA0.u[3] = c[3];
        PA1.u[0] = c[4]; PA1.u[1] = c[5]; PA1.u[2] = c[6]; PA1.u[3] = c[7];
      }
      union { unsigned u[4]; bf16x8 v; } PB0, PB1;
      {
        unsigned c[8];
        float rs0 = 0.f, rs1 = 0.f;
        #pragma unroll
        for (int r = 0; r < 8; r++) {
          float pe = exp2f(sB[2 * r]);
          float po = exp2f(sB[2 * r + 1]);
          if (r & 1) rs1 += pe + po; else rs0 += pe + po;
          asm("v_cvt_pk_bf16_f32 %0, %1, %2" : "=v"(c[r]) : "v"(pe), "v"(po));
        }
        liB += rs0 + rs1;
        asm volatile("v_permlane32_swap_b32 %0, %1" : "+v"(c[0]), "+v"(c[2]));
        asm volatile("v_permlane32_swap_b32 %0, %1" : "+v"(c[1]), "+v"(c[3]));
        asm volatile("v_permlane32_swap_b32 %0, %1" : "+v"(c[4]), "+v"(c[6]));
        asm volatile("v_permlane32_swap_b32 %0, %1" : "+v"(c[5]), "+v"(c[7]));
        PB0.u[0] = c[0]; PB0.u[1] = c[1]; PB0.u[2] = c[2]; PB0.u[3] = c[3];
        PB1.u[0] = c[4]; PB1.u[1] = c[5]; PB1.u[2] = c[6]; PB1.u[3] = c[7];
      }

      int slot0 = (sub << 2) + hi;
      int slot1 = (sub << 2) + 2 + hi;
      bf16x8 v00 = *(const bf16x8*)&Vc[l31 * 64 + ((slot0 ^ (l31 & 7)) << 3)];
      bf16x8 v01 = *(const bf16x8*)&Vc[(32 + l31) * 64 + ((slot0 ^ (l31 & 7)) << 3)];
      bf16x8 v10 = *(const bf16x8*)&Vc[l31 * 64 + ((slot1 ^ (l31 & 7)) << 3)];
      bf16x8 v11 = *(const bf16x8*)&Vc[(32 + l31) * 64 + ((slot1 ^ (l31 & 7)) << 3)];
      __builtin_amdgcn_s_setprio(1);
      oA0 = __builtin_amdgcn_mfma_f32_32x32x16_bf16(v00, PA0.v, oA0, 0, 0, 0);
      oB0 = __builtin_amdgcn_mfma_f32_32x32x16_bf16(v00, PB0.v, oB0, 0, 0, 0);
      oA1 = __builtin_amdgcn_mfma_f32_32x32x16_bf16(v01, PA0.v, oA1, 0, 0, 0);
      oB1 = __builtin_amdgcn_mfma_f32_32x32x16_bf16(v01, PB0.v, oB1, 0, 0, 0);
      oA0 = __builtin_amdgcn_mfma_f32_32x32x16_bf16(v10, PA1.v, oA0, 0, 0, 0);
      oB0 = __builtin_amdgcn_mfma_f32_32x32x16_bf16(v10, PB1.v, oB0, 0, 0, 0);
      oA1 = __builtin_amdgcn_mfma_f32_32x32x16_bf16(v11, PA1.v, oA1, 0, 0, 0);
      oB1 = __builtin_amdgcn_mfma_f32_32x32x16_bf16(v11, PB1.v, oB1, 0, 0, 0);
      __builtin_amdgcn_s_setprio(0);
    }

    {
      unsigned short* Vd = Vs[cur ^ 1];
      union { bf16x8 v; unsigned u[4]; } a0, a1;
      a0.v = vr0; a1.v = vr1;
      #pragma unroll
      for (int i = 0; i < 4; i++) {
        int d0 = dgr + 2 * i, d1 = d0 + 1;
        unsigned we = (a0.u[i] & 0xffffu) | (a1.u[i] << 16);
        unsigned wo = (a0.u[i] >> 16) | (a1.u[i] & 0xffff0000u);
        *(unsigned*)&Vd[d0 * 64 + ((vslot ^ (d0 & 7)) << 3) + vlo] = we;
        *(unsigned*)&Vd[d1 * 64 + ((vslot ^ (d1 & 7)) << 3) + vlo] = wo;
      }
    }
    __syncthreads();
  }

  liA += __shfl_xor(liA, 32, 64);
  liB += __shfl_xor(liB, 32, 64);
  float invA = 1.f / liA, invB = 1.f / liB;
  unsigned short* aopA = ao + (size_t)(b * S_ + q0 + l31) * D_ + h * 64;
  unsigned short* aopB = aopA + (size_t)128 * D_;
  #pragma unroll
  for (int g = 0; g < 4; g++) {
    union { unsigned short s[4]; uint2 u; } wa0, wa1, wb0, wb1;
    #pragma unroll
    for (int e = 0; e < 4; e++) {
      wa0.s[e] = f2b(oA0[g * 4 + e] * invA);
      wa1.s[e] = f2b(oA1[g * 4 + e] * invA);
      wb0.s[e] = f2b(oB0[g * 4 + e] * invB);
      wb1.s[e] = f2b(oB1[g * 4 + e] * invB);
    }
    int d = g * 8 + hi * 4;
    *(uint2*)&aopA[d] = wa0.u;
    *(uint2*)&aopA[32 + d] = wa1.u;
    *(uint2*)&aopB[d] = wb0.u;
    *(uint2*)&aopB[32 + d] = wb1.u;
  }
}

// ---------------- launch ----------------
extern "C" void kernel_launch(void* const* d_in, const int* in_sizes, int n_in,
                              void* d_out, int out_size, void* d_ws, size_t ws_size,
                              hipStream_t stream) {
  const float* x    = (const float*)d_in[0];
  const float* Wqkv = (const float*)d_in[4];
  const float* Wfc  = (const float*)d_in[5];
  const float* bfc  = (const float*)d_in[6];
  float* out = (float*)d_out;

  char* ws = (char*)d_ws;
  unsigned short* xb    = (unsigned short*)(ws);                         // 16 MiB  [8192][1024]
  unsigned short* qkv   = (unsigned short*)(ws + 16777216);              // 48 MiB  [8192][3072]
  unsigned short* ao    = (unsigned short*)(ws + 67108864);              // 16 MiB  [8192][1024]
  unsigned short* wqkvT = (unsigned short*)(ws + 83886080);              // 6 MiB   [3072][1024]
  unsigned short* wfcT  = (unsigned short*)(ws + 90177536);              // 2 MiB   [1024][1024]

  prologue<<<dim3(8192), dim3(256), 0, stream>>>(x, xb, Wqkv, wqkvT, Wfc, wfcT);
  gemm_bt<<<dim3(64, 24), dim3(256), 0, stream>>>(xb, wqkvT, nullptr, nullptr, qkv, 8192, 3072, 1024);
  flash_attn<<<dim3(64, 8), dim3(256), 0, stream>>>(qkv, ao);
  gemm_bt<<<dim3(64, 8), dim3(256), 0, stream>>>(ao, wfcT, bfc, out, nullptr, 8192, 1024, 1024);
}

// Round 20
// 214.403 us; speedup vs baseline: 1.2905x; 1.2905x over previous
//
#include <hip/hip_runtime.h>
#include <hip/hip_bf16.h>

// MultiHeadAttn: B=4, S=2048, D=1024, H=16, HD=64, scale = sqrt(64) = 8
// Pipeline: fused prologue (x cvt + W transposes) | GEMM1 qkv (3-buf counted-vmcnt) |
//           flash attn v8 (best measured, natural 128 VGPR) | GEMM2 +bias
// R20 = R18 exact (best verified: 217.0 us). Max-free softmax line abandoned after
// three register-allocator failures (R16/R17/R19); no launch_bounds min-waves
// coercion anywhere (cuts unified VGPR+AGPR budget -> spill).

#define S_ 2048
#define D_ 1024

typedef __attribute__((ext_vector_type(4))) float f32x4;
typedef __attribute__((ext_vector_type(16))) float f32x16;
typedef __attribute__((ext_vector_type(8))) short bf16x8;

__device__ __forceinline__ unsigned short f2b(float f) {
  union { float f; unsigned u; } x; x.f = f;
  unsigned r = x.u + 0x7fffu + ((x.u >> 16) & 1u);
  return (unsigned short)(r >> 16);
}
__device__ __forceinline__ float b2f(unsigned short u) {
  union { unsigned u; float f; } x; x.u = ((unsigned)u) << 16; return x.f;
}

__device__ __forceinline__ void gload_lds16(const void* g, void* l) {
  __builtin_amdgcn_global_load_lds(
      (const __attribute__((address_space(1))) unsigned int*)g,
      (__attribute__((address_space(3))) unsigned int*)l, 16, 0, 0);
}

// ---------------- fused prologue: x f32->bf16 + both W transposes ----------------
// grid 8192 x 256: blocks [0,4096) cvt x; [4096,7168) transpose Wqkv; [7168,8192) Wfc.
__global__ __launch_bounds__(256) void prologue(const float* __restrict__ x,
                                                unsigned short* __restrict__ xb,
                                                const float* __restrict__ Wqkv,
                                                unsigned short* __restrict__ wqkvT,
                                                const float* __restrict__ Wfc,
                                                unsigned short* __restrict__ wfcT) {
  __shared__ unsigned short tile[32][33];
  int bid = blockIdx.x;
  if (bid < 4096) {
    int i = (bid * 256 + threadIdx.x) * 8;
    float4 a = *(const float4*)&x[i];
    float4 b = *(const float4*)&x[i + 4];
    unsigned short r[8];
    r[0] = f2b(a.x); r[1] = f2b(a.y); r[2] = f2b(a.z); r[3] = f2b(a.w);
    r[4] = f2b(b.x); r[5] = f2b(b.y); r[6] = f2b(b.z); r[7] = f2b(b.w);
    *(uint4*)&xb[i] = *(uint4*)r;
    return;
  }
  const float* W; unsigned short* Wt; int N, n0, k0;
  if (bid < 7168) {
    int t = bid - 4096;
    W = Wqkv; Wt = wqkvT; N = 3072;
    n0 = (t % 96) * 32; k0 = (t / 96) * 32;
  } else {
    int t = bid - 7168;
    W = Wfc; Wt = wfcT; N = 1024;
    n0 = (t % 32) * 32; k0 = (t / 32) * 32;
  }
  int tx = threadIdx.x & 31, ty = threadIdx.x >> 5;  // 32 x 8
  #pragma unroll
  for (int i = 0; i < 32; i += 8)
    tile[ty + i][tx] = f2b(W[(size_t)(k0 + ty + i) * N + n0 + tx]);
  __syncthreads();
  #pragma unroll
  for (int i = 0; i < 32; i += 8)
    Wt[(size_t)(n0 + ty + i) * 1024 + k0 + tx] = tile[tx][ty + i];
}

// ---------------- GEMM: C[M][N] = A[M][K] * Bt[N][K]^T (R13/R15/R18 exact) ----------------
// 3-buffer counted-vmcnt pipeline: STAGE(kt+2); vmcnt(8); barrier; ds_read+MFMA;
// lgkmcnt(0); barrier. vmcnt never drains to 0 mid-loop. K must be 1024.
__global__ __launch_bounds__(256) void gemm_bt(const unsigned short* __restrict__ A,
                                               const unsigned short* __restrict__ Bt,
                                               const float* __restrict__ bias,
                                               float* __restrict__ Cf,
                                               unsigned short* __restrict__ Cb,
                                               int M, int N, int K) {
  __shared__ unsigned short As[3][128 * 32];
  __shared__ unsigned short Bs[3][128 * 32];
  int tid = threadIdx.x, wave = tid >> 6, lane = tid & 63;
  int bm = blockIdx.x, bn = blockIdx.y;
  int wr = (wave >> 1) * 64, wc = (wave & 1) * 64;
  f32x4 acc[4][4] = {};

  const unsigned short* aBase = A + (size_t)(bm * 128 + wave * 32 + (lane >> 2)) * K + (lane & 3) * 8;
  const unsigned short* bBase = Bt + (size_t)(bn * 128 + wave * 32 + (lane >> 2)) * K + (lane & 3) * 8;
  const size_t row16 = (size_t)16 * K;
  int ldst0 = wave * 1024 + lane * 8;
  int ldst1 = ldst0 + 512;

  #define STAGE_G(kt, sb)                                                      \
    do {                                                                       \
      const unsigned short* ap = aBase + (kt) * 32;                            \
      const unsigned short* bp = bBase + (kt) * 32;                            \
      gload_lds16(ap, &As[sb][ldst0]);                                         \
      gload_lds16(ap + row16, &As[sb][ldst1]);                                 \
      gload_lds16(bp, &Bs[sb][ldst0]);                                         \
      gload_lds16(bp + row16, &Bs[sb][ldst1]);                                 \
    } while (0)

  #define READ_MFMA_G(sb)                                                      \
    do {                                                                       \
      bf16x8 af[4], bf[4];                                                     \
      _Pragma("unroll")                                                        \
      for (int i = 0; i < 4; i++)                                              \
        af[i] = *(const bf16x8*)&As[sb][(wr + i * 16 + (lane & 15)) * 32 + (lane >> 4) * 8]; \
      _Pragma("unroll")                                                        \
      for (int i = 0; i < 4; i++)                                              \
        bf[i] = *(const bf16x8*)&Bs[sb][(wc + i * 16 + (lane & 15)) * 32 + (lane >> 4) * 8]; \
      _Pragma("unroll")                                                        \
      for (int i = 0; i < 4; i++)                                              \
        _Pragma("unroll")                                                      \
        for (int j = 0; j < 4; j++)                                            \
          acc[i][j] = __builtin_amdgcn_mfma_f32_16x16x32_bf16(af[i], bf[j], acc[i][j], 0, 0, 0); \
    } while (0)

  #define TRAIL_SYNC()                                                         \
    do {                                                                       \
      asm volatile("s_waitcnt lgkmcnt(0)" ::: "memory");                       \
      asm volatile("s_barrier" ::: "memory");                                  \
    } while (0)

  STAGE_G(0, 0);
  STAGE_G(1, 1);
  asm volatile("s_waitcnt vmcnt(4)" ::: "memory");
  asm volatile("s_barrier" ::: "memory");

  for (int t3 = 0; t3 < 10; ++t3) {
    int kt = t3 * 3;
    STAGE_G(kt + 2, 2);
    asm volatile("s_waitcnt vmcnt(8)" ::: "memory");
    asm volatile("s_barrier" ::: "memory");
    READ_MFMA_G(0);
    TRAIL_SYNC();
    STAGE_G(kt + 3, 0);
    asm volatile("s_waitcnt vmcnt(8)" ::: "memory");
    asm volatile("s_barrier" ::: "memory");
    READ_MFMA_G(1);
    TRAIL_SYNC();
    STAGE_G(kt + 4, 1);
    asm volatile("s_waitcnt vmcnt(8)" ::: "memory");
    asm volatile("s_barrier" ::: "memory");
    READ_MFMA_G(2);
    TRAIL_SYNC();
  }
  asm volatile("s_waitcnt vmcnt(4)" ::: "memory");
  asm volatile("s_barrier" ::: "memory");
  READ_MFMA_G(0);
  TRAIL_SYNC();
  asm volatile("s_waitcnt vmcnt(0)" ::: "memory");
  asm volatile("s_barrier" ::: "memory");
  READ_MFMA_G(1);
  #undef STAGE_G
  #undef READ_MFMA_G
  #undef TRAIL_SYNC

  int row0 = bm * 128 + wr + (lane >> 4) * 4;
  int col0 = bn * 128 + wc + (lane & 15);
  if (Cb) {
    #pragma unroll
    for (int i = 0; i < 4; i++)
      #pragma unroll
      for (int j = 0; j < 4; j++)
        #pragma unroll
        for (int q = 0; q < 4; q++)
          Cb[(size_t)(row0 + i * 16 + q) * N + col0 + j * 16] = f2b(acc[i][j][q]);
  } else {
    #pragma unroll
    for (int i = 0; i < 4; i++)
      #pragma unroll
      for (int j = 0; j < 4; j++) {
        float bv = bias[col0 + j * 16];
        #pragma unroll
        for (int q = 0; q < 4; q++)
          Cf[(size_t)(row0 + i * 16 + q) * N + col0 + j * 16] = acc[i][j][q] + bv;
      }
  }
}

// ---------------- flash attention v8 (best measured: 118.4 us) ----------------
// grid (64 heads, 8 q-blocks of 256): XCD = bh%8 -> per-XCD K/V L2-resident (T1).
// block 256 = 4 waves; each wave owns q-rows [q0, q0+32) and [q0+128, q0+160).
// K/V-frags LDS-read once, used for both Q-tiles. Softmax per v4 (T12/T13).
// V staging: paired-b32 swizzled writes. Natural allocation = exactly 128 VGPR.
__global__ __launch_bounds__(256) void flash_attn(const unsigned short* __restrict__ qkv,
                                                  unsigned short* __restrict__ ao) {
  __shared__ unsigned short Ks[2][4096];   // [64 kv][64 d], 16B-slot ^ (row&7) swizzle
  __shared__ unsigned short Vs[2][4096];   // [64 d][64 kv], same swizzle
  int tid = threadIdx.x, wave = tid >> 6, lane = tid & 63;
  int l31 = lane & 31, hi = lane >> 5;
  int bh = blockIdx.x, b = bh >> 4, h = bh & 15;
  const unsigned short* base = qkv + (size_t)b * S_ * 3072 + h * 64;
  const unsigned short* kb = base + 1024;
  const unsigned short* vb = base + 2048;
  int q0 = blockIdx.y * 256 + wave * 32;   // tile A; tile B = q0 + 128

  bf16x8 qfA[4], qfB[4];
  {
    const unsigned short* qpA = base + (size_t)(q0 + l31) * 3072 + hi * 8;
    const unsigned short* qpB = qpA + (size_t)128 * 3072;
    #pragma unroll
    for (int ks = 0; ks < 4; ks++) {
      bf16x8 va = *(const bf16x8*)(qpA + ks * 16);
      bf16x8 vc = *(const bf16x8*)(qpB + ks * 16);
      #pragma unroll
      for (int e = 0; e < 8; e++) {
        va[e] = (short)f2b(0.125f * b2f((unsigned short)va[e]));
        vc[e] = (short)f2b(0.125f * b2f((unsigned short)vc[e]));
      }
      qfA[ks] = va; qfB[ks] = vc;
    }
  }

  f32x16 oA0 = {}, oA1 = {}, oB0 = {}, oB1 = {};
  float miA = -1e30f, liA = 0.f, miB = -1e30f, liB = 0.f;

  int r_l = lane >> 3;
  int gsrc = (lane & 7) ^ r_l;
  size_t koffA = (size_t)((wave * 2 + 0) * 8 + r_l) * 3072 + gsrc * 8;
  size_t koffB = (size_t)((wave * 2 + 1) * 8 + r_l) * 3072 + gsrc * 8;
  int kvp = (tid & 31) * 2, dgr = (tid >> 5) * 8;
  int vslot = kvp >> 3;
  int vlo = kvp & 7;
  bf16x8 vr0, vr1;

  {
    gload_lds16(kb + koffA, &Ks[0][(wave * 2 + 0) * 512]);
    gload_lds16(kb + koffB, &Ks[0][(wave * 2 + 1) * 512]);
    const unsigned short* vsrc = vb + (size_t)kvp * 3072 + dgr;
    vr0 = *(const bf16x8*)vsrc;
    vr1 = *(const bf16x8*)(vsrc + 3072);
    union { bf16x8 v; unsigned u[4]; } a0, a1;
    a0.v = vr0; a1.v = vr1;
    #pragma unroll
    for (int i = 0; i < 4; i++) {
      int d0 = dgr + 2 * i, d1 = d0 + 1;
      unsigned we = (a0.u[i] & 0xffffu) | (a1.u[i] << 16);
      unsigned wo = (a0.u[i] >> 16) | (a1.u[i] & 0xffff0000u);
      *(unsigned*)&Vs[0][d0 * 64 + ((vslot ^ (d0 & 7)) << 3) + vlo] = we;
      *(unsigned*)&Vs[0][d1 * 64 + ((vslot ^ (d1 & 7)) << 3) + vlo] = wo;
    }
    __syncthreads();
  }

  for (int t = 0; t < 32; ++t) {
    int cur = t & 1;
    int tn = (t + 1) & 31;
    {
      const unsigned short* ksrc = kb + (size_t)tn * 64 * 3072;
      gload_lds16(ksrc + koffA, &Ks[cur ^ 1][(wave * 2 + 0) * 512]);
      gload_lds16(ksrc + koffB, &Ks[cur ^ 1][(wave * 2 + 1) * 512]);
      const unsigned short* vsrc = vb + (size_t)(tn * 64 + kvp) * 3072 + dgr;
      vr0 = *(const bf16x8*)vsrc;
      vr1 = *(const bf16x8*)(vsrc + 3072);
    }

    const unsigned short* Kc = Ks[cur];
    const unsigned short* Vc = Vs[cur];

    #pragma unroll
    for (int sub = 0; sub < 2; ++sub) {
      f32x16 sA = {}, sB = {};
      __builtin_amdgcn_s_setprio(1);
      #pragma unroll
      for (int ks = 0; ks < 4; ks++) {
        int row = sub * 32 + l31;
        bf16x8 kf = *(const bf16x8*)&Kc[row * 64 + ((((ks << 1) + hi) ^ (row & 7)) << 3)];
        sA = __builtin_amdgcn_mfma_f32_32x32x16_bf16(kf, qfA[ks], sA, 0, 0, 0);
        sB = __builtin_amdgcn_mfma_f32_32x32x16_bf16(kf, qfB[ks], sB, 0, 0, 0);
      }
      __builtin_amdgcn_s_setprio(0);

      union { unsigned u[4]; bf16x8 v; } PA0, PA1;
      {
        float t0 = fmaxf(fmaxf(sA[0], sA[1]), sA[2]);
        float t1 = fmaxf(fmaxf(sA[3], sA[4]), sA[5]);
        float t2 = fmaxf(fmaxf(sA[6], sA[7]), sA[8]);
        float t3 = fmaxf(fmaxf(sA[9], sA[10]), sA[11]);
        float t4 = fmaxf(fmaxf(sA[12], sA[13]), sA[14]);
        float tm = fmaxf(fmaxf(fmaxf(t0, t1), t2), fmaxf(fmaxf(t3, t4), sA[15]));
        tm = fmaxf(tm, __shfl_xor(tm, 32, 64));
        if (__any(tm > miA + 8.f)) {
          float tnew = fmaxf(miA, tm);
          float fac = __expf(miA - tnew);
          liA *= fac; miA = tnew;
          #pragma unroll
          for (int r = 0; r < 16; r++) { oA0[r] *= fac; oA1[r] *= fac; }
        }
        float p[16];
        float rs = 0.f;
        #pragma unroll
        for (int r = 0; r < 16; r++) { p[r] = __expf(sA[r] - miA); rs += p[r]; }
        liA += rs;
        unsigned c0, c1, c2, c3, c4, c5, c6, c7;
        asm("v_cvt_pk_bf16_f32 %0, %1, %2" : "=v"(c0) : "v"(p[0]),  "v"(p[1]));
        asm("v_cvt_pk_bf16_f32 %0, %1, %2" : "=v"(c1) : "v"(p[2]),  "v"(p[3]));
        asm("v_cvt_pk_bf16_f32 %0, %1, %2" : "=v"(c2) : "v"(p[4]),  "v"(p[5]));
        asm("v_cvt_pk_bf16_f32 %0, %1, %2" : "=v"(c3) : "v"(p[6]),  "v"(p[7]));
        asm("v_cvt_pk_bf16_f32 %0, %1, %2" : "=v"(c4) : "v"(p[8]),  "v"(p[9]));
        asm("v_cvt_pk_bf16_f32 %0, %1, %2" : "=v"(c5) : "v"(p[10]), "v"(p[11]));
        asm("v_cvt_pk_bf16_f32 %0, %1, %2" : "=v"(c6) : "v"(p[12]), "v"(p[13]));
        asm("v_cvt_pk_bf16_f32 %0, %1, %2" : "=v"(c7) : "v"(p[14]), "v"(p[15]));
        asm volatile("v_permlane32_swap_b32 %0, %1" : "+v"(c0), "+v"(c2));
        asm volatile("v_permlane32_swap_b32 %0, %1" : "+v"(c1), "+v"(c3));
        asm volatile("v_permlane32_swap_b32 %0, %1" : "+v"(c4), "+v"(c6));
        asm volatile("v_permlane32_swap_b32 %0, %1" : "+v"(c5), "+v"(c7));
        PA0.u[0] = c0; PA0.u[1] = c1; PA0.u[2] = c2; PA0.u[3] = c3;
        PA1.u[0] = c4; PA1.u[1] = c5; PA1.u[2] = c6; PA1.u[3] = c7;
      }
      union { unsigned u[4]; bf16x8 v; } PB0, PB1;
      {
        float t0 = fmaxf(fmaxf(sB[0], sB[1]), sB[2]);
        float t1 = fmaxf(fmaxf(sB[3], sB[4]), sB[5]);
        float t2 = fmaxf(fmaxf(sB[6], sB[7]), sB[8]);
        float t3 = fmaxf(fmaxf(sB[9], sB[10]), sB[11]);
        float t4 = fmaxf(fmaxf(sB[12], sB[13]), sB[14]);
        float tm = fmaxf(fmaxf(fmaxf(t0, t1), t2), fmaxf(fmaxf(t3, t4), sB[15]));
        tm = fmaxf(tm, __shfl_xor(tm, 32, 64));
        if (__any(tm > miB + 8.f)) {
          float tnew = fmaxf(miB, tm);
          float fac = __expf(miB - tnew);
          liB *= fac; miB = tnew;
          #pragma unroll
          for (int r = 0; r < 16; r++) { oB0[r] *= fac; oB1[r] *= fac; }
        }
        float p[16];
        float rs = 0.f;
        #pragma unroll
        for (int r = 0; r < 16; r++) { p[r] = __expf(sB[r] - miB); rs += p[r]; }
        liB += rs;
        unsigned c0, c1, c2, c3, c4, c5, c6, c7;
        asm("v_cvt_pk_bf16_f32 %0, %1, %2" : "=v"(c0) : "v"(p[0]),  "v"(p[1]));
        asm("v_cvt_pk_bf16_f32 %0, %1, %2" : "=v"(c1) : "v"(p[2]),  "v"(p[3]));
        asm("v_cvt_pk_bf16_f32 %0, %1, %2" : "=v"(c2) : "v"(p[4]),  "v"(p[5]));
        asm("v_cvt_pk_bf16_f32 %0, %1, %2" : "=v"(c3) : "v"(p[6]),  "v"(p[7]));
        asm("v_cvt_pk_bf16_f32 %0, %1, %2" : "=v"(c4) : "v"(p[8]),  "v"(p[9]));
        asm("v_cvt_pk_bf16_f32 %0, %1, %2" : "=v"(c5) : "v"(p[10]), "v"(p[11]));
        asm("v_cvt_pk_bf16_f32 %0, %1, %2" : "=v"(c6) : "v"(p[12]), "v"(p[13]));
        asm("v_cvt_pk_bf16_f32 %0, %1, %2" : "=v"(c7) : "v"(p[14]), "v"(p[15]));
        asm volatile("v_permlane32_swap_b32 %0, %1" : "+v"(c0), "+v"(c2));
        asm volatile("v_permlane32_swap_b32 %0, %1" : "+v"(c1), "+v"(c3));
        asm volatile("v_permlane32_swap_b32 %0, %1" : "+v"(c4), "+v"(c6));
        asm volatile("v_permlane32_swap_b32 %0, %1" : "+v"(c5), "+v"(c7));
        PB0.u[0] = c0; PB0.u[1] = c1; PB0.u[2] = c2; PB0.u[3] = c3;
        PB1.u[0] = c4; PB1.u[1] = c5; PB1.u[2] = c6; PB1.u[3] = c7;
      }

      int slot0 = (sub << 2) + hi;
      int slot1 = (sub << 2) + 2 + hi;
      bf16x8 v00 = *(const bf16x8*)&Vc[l31 * 64 + ((slot0 ^ (l31 & 7)) << 3)];
      bf16x8 v01 = *(const bf16x8*)&Vc[(32 + l31) * 64 + ((slot0 ^ (l31 & 7)) << 3)];
      bf16x8 v10 = *(const bf16x8*)&Vc[l31 * 64 + ((slot1 ^ (l31 & 7)) << 3)];
      bf16x8 v11 = *(const bf16x8*)&Vc[(32 + l31) * 64 + ((slot1 ^ (l31 & 7)) << 3)];
      __builtin_amdgcn_s_setprio(1);
      oA0 = __builtin_amdgcn_mfma_f32_32x32x16_bf16(v00, PA0.v, oA0, 0, 0, 0);
      oB0 = __builtin_amdgcn_mfma_f32_32x32x16_bf16(v00, PB0.v, oB0, 0, 0, 0);
      oA1 = __builtin_amdgcn_mfma_f32_32x32x16_bf16(v01, PA0.v, oA1, 0, 0, 0);
      oB1 = __builtin_amdgcn_mfma_f32_32x32x16_bf16(v01, PB0.v, oB1, 0, 0, 0);
      oA0 = __builtin_amdgcn_mfma_f32_32x32x16_bf16(v10, PA1.v, oA0, 0, 0, 0);
      oB0 = __builtin_amdgcn_mfma_f32_32x32x16_bf16(v10, PB1.v, oB0, 0, 0, 0);
      oA1 = __builtin_amdgcn_mfma_f32_32x32x16_bf16(v11, PA1.v, oA1, 0, 0, 0);
      oB1 = __builtin_amdgcn_mfma_f32_32x32x16_bf16(v11, PB1.v, oB1, 0, 0, 0);
      __builtin_amdgcn_s_setprio(0);
    }

    {
      unsigned short* Vd = Vs[cur ^ 1];
      union { bf16x8 v; unsigned u[4]; } a0, a1;
      a0.v = vr0; a1.v = vr1;
      #pragma unroll
      for (int i = 0; i < 4; i++) {
        int d0 = dgr + 2 * i, d1 = d0 + 1;
        unsigned we = (a0.u[i] & 0xffffu) | (a1.u[i] << 16);
        unsigned wo = (a0.u[i] >> 16) | (a1.u[i] & 0xffff0000u);
        *(unsigned*)&Vd[d0 * 64 + ((vslot ^ (d0 & 7)) << 3) + vlo] = we;
        *(unsigned*)&Vd[d1 * 64 + ((vslot ^ (d1 & 7)) << 3) + vlo] = wo;
      }
    }
    __syncthreads();
  }

  liA += __shfl_xor(liA, 32, 64);
  liB += __shfl_xor(liB, 32, 64);
  float invA = 1.f / liA, invB = 1.f / liB;
  unsigned short* aopA = ao + (size_t)(b * S_ + q0 + l31) * D_ + h * 64;
  unsigned short* aopB = aopA + (size_t)128 * D_;
  #pragma unroll
  for (int g = 0; g < 4; g++) {
    union { unsigned short s[4]; uint2 u; } wa0, wa1, wb0, wb1;
    #pragma unroll
    for (int e = 0; e < 4; e++) {
      wa0.s[e] = f2b(oA0[g * 4 + e] * invA);
      wa1.s[e] = f2b(oA1[g * 4 + e] * invA);
      wb0.s[e] = f2b(oB0[g * 4 + e] * invB);
      wb1.s[e] = f2b(oB1[g * 4 + e] * invB);
    }
    int d = g * 8 + hi * 4;
    *(uint2*)&aopA[d] = wa0.u;
    *(uint2*)&aopA[32 + d] = wa1.u;
    *(uint2*)&aopB[d] = wb0.u;
    *(uint2*)&aopB[32 + d] = wb1.u;
  }
}

// ---------------- launch ----------------
extern "C" void kernel_launch(void* const* d_in, const int* in_sizes, int n_in,
                              void* d_out, int out_size, void* d_ws, size_t ws_size,
                              hipStream_t stream) {
  const float* x    = (const float*)d_in[0];
  const float* Wqkv = (const float*)d_in[4];
  const float* Wfc  = (const float*)d_in[5];
  const float* bfc  = (const float*)d_in[6];
  float* out = (float*)d_out;

  char* ws = (char*)d_ws;
  unsigned short* xb    = (unsigned short*)(ws);                         // 16 MiB  [8192][1024]
  unsigned short* qkv   = (unsigned short*)(ws + 16777216);              // 48 MiB  [8192][3072]
  unsigned short* ao    = (unsigned short*)(ws + 67108864);              // 16 MiB  [8192][1024]
  unsigned short* wqkvT = (unsigned short*)(ws + 83886080);              // 6 MiB   [3072][1024]
  unsigned short* wfcT  = (unsigned short*)(ws + 90177536);              // 2 MiB   [1024][1024]

  prologue<<<dim3(8192), dim3(256), 0, stream>>>(x, xb, Wqkv, wqkvT, Wfc, wfcT);
  gemm_bt<<<dim3(64, 24), dim3(256), 0, stream>>>(xb, wqkvT, nullptr, nullptr, qkv, 8192, 3072, 1024);
  flash_attn<<<dim3(64, 8), dim3(256), 0, stream>>>(qkv, ao);
  gemm_bt<<<dim3(64, 8), dim3(256), 0, stream>>>(ao, wfcT, bfc, out, nullptr, 8192, 1024, 1024);
}